// Round 3
// baseline (124.803 us; speedup 1.0000x reference)
//
#include <hip/hip_runtime.h>
#include <cstdint>
#include <cstddef>

// out[64,197,768] = concat(cls, patchify(images[64,3,224,224]) @ W^T + b)
// R3: image prepass ELIMINATED — GEMM gathers fp32 images directly (patchify
// fused into A-staging, in-register cvt to bf16, padded-LDS ds_write_b128).
// Prep kernel only converts W->bf16 (2.4 MB) and writes cls rows.
#define MTOT 12544   // 64*196
#define KTOT 768

typedef float  f32x4  __attribute__((ext_vector_type(4)));
typedef __bf16 bf16x8 __attribute__((ext_vector_type(8)));

// ---------------- Prep: W fp32->bf16 + cls rows (tiny) ----------------
#define W_BLOCKS   288   // 768*768/8/256
#define CLS_BLOCKS 48    // 64*768/4/256

__global__ __launch_bounds__(256) void prep_kernel(
    const float* __restrict__ Wm, const float* __restrict__ cls,
    float* __restrict__ out, __bf16* __restrict__ Wb) {
  const int bid = blockIdx.x, tid = threadIdx.x;
  if (bid < W_BLOCKS) {
    const size_t q = (size_t)bid * 256 + tid;
    const float4 v0 = *(const float4*)(Wm + q * 8);
    const float4 v1 = *(const float4*)(Wm + q * 8 + 4);
    bf16x8 o;
    o[0]=(__bf16)v0.x; o[1]=(__bf16)v0.y; o[2]=(__bf16)v0.z; o[3]=(__bf16)v0.w;
    o[4]=(__bf16)v1.x; o[5]=(__bf16)v1.y; o[6]=(__bf16)v1.z; o[7]=(__bf16)v1.w;
    *(bf16x8*)(Wb + q * 8) = o;
  } else {
    const int t  = (bid - W_BLOCKS) * 256 + tid;
    const int bb = t / 192;             // 192 float4 per 768-row
    const int r  = t - bb * 192;
    *(float4*)(out + (size_t)bb * 197 * 768 + r * 4) = *(const float4*)(cls + r * 4);
  }
}

// ---------------- GEMM: fused patchify + cvt + MFMA ----------------
// BM=64, BN=128, BK=64 -> grid 196*6 = 1176 = 8*147 blocks (XCD-swizzled).
// A: padded LDS [ks][64][40] via ds_write_b128 (stride-40 => uniform banks).
// B: global_load_lds width-16 from bf16 W, unpadded [ks][128][32].
#define BM 64
#define BN 128
#define APAD 40
#define NBLK_N 6

__device__ __forceinline__ void gload_lds16(const void* g, void* l) {
  __builtin_amdgcn_global_load_lds((__attribute__((address_space(1))) void*)(g),
                                   (__attribute__((address_space(3))) void*)(l),
                                   16, 0, 0);
}

__global__ __launch_bounds__(256) void gemm_kernel(
    const float* __restrict__ images, const __bf16* __restrict__ Wb,
    const float* __restrict__ bias, float* __restrict__ out) {
  __shared__ __bf16 As[2 * BM * APAD];  // 10.0 KB
  __shared__ __bf16 Bs[2 * BN * 32];    // 16.0 KB

  const int tid = threadIdx.x;
  // XCD swizzle: XCD x = bx%8 gets slots s=bx/8 in order; siblings (same mblk,
  // nblk 0..5) are consecutive in g => A tile stays in that XCD's L2.
  const int g    = (blockIdx.x & 7) * 147 + (blockIdx.x >> 3);
  const int mblk = g / NBLK_N, nblk = g - mblk * NBLK_N;
  const int m0 = mblk * BM, n0 = nblk * BN;
  const int wave = tid >> 6, lane = tid & 63;
  const int wm = (wave & 1) * 32, wn = (wave >> 1) * 64;
  const int lrow = lane & 15, lq = lane >> 4;

  // --- A gather setup: thread owns (row=lane, kseg16=wave): 16 consecutive k
  // = one 16-px image row segment = 64 B contiguous fp32.
  const int row = lane;
  const int m  = m0 + row;
  const int bb = m / 196, p = m - bb * 196;
  const int pi = p / 14,  pj = p - pi * 14;
  // kt=0: c=0, ph=wave
  const float* gA = images +
      ((size_t)(bb * 3) * 224 + (size_t)(pi * 16 + wave)) * 224 + pj * 16;
  const int aks = wave >> 1, akoff = (wave & 1) * 16;
  __bf16* wA = &As[(aks * BM + row) * APAD + akoff];

  // --- B staging: 1024 chunks of 16 B; thread handles 4 (wave-uniform LDS base)
  const __bf16* pB[4];
  __bf16* lB[4];
#pragma unroll
  for (int s = 0; s < 4; ++s) {
    const int c  = wave * 256 + s * 64 + lane;
    const int ks = c >> 9, rem = c & 511, h = rem >> 2, jc = rem & 3;
    pB[s] = Wb + (size_t)(n0 + h) * 768 + ks * 32 + jc * 8;
    lB[s] = Bs + (size_t)(wave * 256 + s * 64) * 8;
  }

  f32x4 acc[2][4] = {};

  for (int kt = 0; kt < 12; ++kt) {
    // B: async global->LDS (issue first, longest queue)
#pragma unroll
    for (int s = 0; s < 4; ++s) gload_lds16(pB[s], lB[s]);
    // A: fp32 gather -> cvt -> padded LDS
    const float4 v0 = *(const float4*)(gA);
    const float4 v1 = *(const float4*)(gA + 4);
    const float4 v2 = *(const float4*)(gA + 8);
    const float4 v3 = *(const float4*)(gA + 12);
    bf16x8 o0, o1;
    o0[0]=(__bf16)v0.x; o0[1]=(__bf16)v0.y; o0[2]=(__bf16)v0.z; o0[3]=(__bf16)v0.w;
    o0[4]=(__bf16)v1.x; o0[5]=(__bf16)v1.y; o0[6]=(__bf16)v1.z; o0[7]=(__bf16)v1.w;
    o1[0]=(__bf16)v2.x; o1[1]=(__bf16)v2.y; o1[2]=(__bf16)v2.z; o1[3]=(__bf16)v2.w;
    o1[4]=(__bf16)v3.x; o1[5]=(__bf16)v3.y; o1[6]=(__bf16)v3.z; o1[7]=(__bf16)v3.w;
    *(bf16x8*)(wA)     = o0;
    *(bf16x8*)(wA + 8) = o1;
    // advance: +4 image rows; at channel crossing (kt%4==3): next channel
    gA += ((kt & 3) == 3) ? 47488 : 896;   // 224*224-12*224 : 4*224
    pB[0] += 64; pB[1] += 64; pB[2] += 64; pB[3] += 64;
    __syncthreads();   // drains vmcnt (gload_lds) + lgkmcnt (ds_write)

#pragma unroll
    for (int ks = 0; ks < 2; ++ks) {
      bf16x8 af[2], bf[4];
#pragma unroll
      for (int i = 0; i < 2; ++i)
        af[i] = *(const bf16x8*)&As[(ks * BM + wm + i * 16 + lrow) * APAD + lq * 8];
#pragma unroll
      for (int j = 0; j < 4; ++j)
        bf[j] = *(const bf16x8*)&Bs[(ks * BN + wn + j * 16 + lrow) * 32 + lq * 8];
#pragma unroll
      for (int i = 0; i < 2; ++i)
#pragma unroll
        for (int j = 0; j < 4; ++j)
          acc[i][j] = __builtin_amdgcn_mfma_f32_16x16x32_bf16(af[i], bf[j], acc[i][j], 0, 0, 0);
    }
    __syncthreads();
  }

  // Epilogue: C/D layout col=lane&15, row=(lane>>4)*4+r; scatter past cls token.
#pragma unroll
  for (int j = 0; j < 4; ++j) {
    const int h  = n0 + wn + j * 16 + lrow;
    const float bv = bias[h];
#pragma unroll
    for (int i = 0; i < 2; ++i) {
      const int mb = m0 + wm + i * 16 + lq * 4;
#pragma unroll
      for (int r = 0; r < 4; ++r) {
        const int mm  = mb + r;
        const int bb2 = mm / 196, p2 = mm - bb2 * 196;
        out[(size_t)(bb2 * 197 + 1 + p2) * 768 + h] = acc[i][j][r] + bv;
      }
    }
  }
}

extern "C" void kernel_launch(void* const* d_in, const int* in_sizes, int n_in,
                              void* d_out, int out_size, void* d_ws, size_t ws_size,
                              hipStream_t stream) {
  const float* images = (const float*)d_in[0];  // [64,3,224,224]
  const float* Wm     = (const float*)d_in[1];  // [768,768]
  const float* b      = (const float*)d_in[2];  // [768]
  const float* cls    = (const float*)d_in[3];  // [1,768]
  float* out = (float*)d_out;                   // [64,197,768]
  __bf16* Wb = (__bf16*)d_ws;                   // 1.18 MB
  (void)in_sizes; (void)n_in; (void)out_size; (void)ws_size;

  prep_kernel<<<W_BLOCKS + CLS_BLOCKS, 256, 0, stream>>>(Wm, cls, out, Wb);
  gemm_kernel<<<(MTOT / BM) * NBLK_N, 256, 0, stream>>>(images, Wb, b, out);
}